// Round 1
// 308.916 us; speedup vs baseline: 1.0383x; 1.0383x over previous
//
#include <hip/hip_runtime.h>
#include <hip/hip_bf16.h>
#include <stdint.h>

// ReadoutLayer: Wx = x @ W^T (+b cancels under BN), BatchNorm(train) over B*T,
// then ut = a*ut + (1-a)*wxn per t with acc += softmax(ut, axis=H).
// R5: kill gemm_k LDS bank conflicts. Old [row][32k] tiles had 64B row stride ->
// fragment reads (lane=row) hit banks {0-3,16-19} only (~4x multiplier,
// SQ_LDS_BANK_CONFLICT=1.5e7, MfmaUtil=13%). New K-major chunk layout
// Bs2[kq][col][8k] / As2[kq][row+pad][8k]: lane -> consecutive 16B chunks,
// conflict-free. B staging stays linear on BOTH sides (rule #21) by
// pre-permuting Wbf in wcvt_k (Wbf2[k8][h][8], one-time 0.5MB transpose).
// Wave mapping 1rtx4ct -> 2rtx2ct: 8 ds_reads per 8 MFMA (was 10).
// LDS data is bit-identical to R4 -> results bit-identical.

namespace {
constexpr int kB = 32;
constexpr int kT = 2000;
constexpr int kD = 512;
constexpr int kH = 512;
constexpr int kM = kB * kT;   // 64000 rows
constexpr int kL = 20;        // chunk length
constexpr int kC = kT / kL;   // 100 chunks per batch
constexpr float kALo = 0.81873075307798182f;  // exp(-1/5)
constexpr float kAHi = 0.96078943915232320f;  // exp(-1/25)

typedef __bf16 bf16x4 __attribute__((ext_vector_type(4)));
typedef __bf16 bf16x8 __attribute__((ext_vector_type(8)));
typedef float floatx16 __attribute__((ext_vector_type(16)));

__device__ __forceinline__ float bf2f(unsigned short u) {
  return __builtin_bit_cast(float, (unsigned)u << 16);
}
__device__ __forceinline__ float clipa(float a) {
  return fminf(fmaxf(a, kALo), kAHi);
}
__device__ __forceinline__ float pow20(float a) {
  const float a2 = a * a, a4 = a2 * a2, a5 = a4 * a;
  const float a10 = a5 * a5;
  return a10 * a10;
}
// async global->LDS, 16B per lane; LDS dest = wave-uniform base + lane*16
__device__ __forceinline__ void gld_lds16(const void* g, void* l) {
  __builtin_amdgcn_global_load_lds(
      (const __attribute__((address_space(1))) uint32_t*)g,
      (__attribute__((address_space(3))) uint32_t*)(uintptr_t)l, 16, 0, 0);
}

// ---------- K0: W f32 -> bf16, permuted to Wbf2[k8][h][8] (k8 = k/8) ----------
// Per slab s, kq=(k/8)&3: slab-local chunk index = kq*512 + h = linear in
// global chunk index (s*4+kq)*512 + h = k8*512 + h. So gemm B-staging reads
// lane-consecutive 16B chunks -> linear LDS dest (global_load_lds-legal).
__global__ __launch_bounds__(256) void wcvt_k(const float* __restrict__ W,
                                              __bf16* __restrict__ Wbf) {
  const int t = blockIdx.x * 256 + threadIdx.x;  // t = h*64 + k8
  const float4 a0 = ((const float4*)W)[t * 2];
  const float4 a1 = ((const float4*)W)[t * 2 + 1];
  bf16x8 v;
  v[0] = (__bf16)a0.x; v[1] = (__bf16)a0.y; v[2] = (__bf16)a0.z; v[3] = (__bf16)a0.w;
  v[4] = (__bf16)a1.x; v[5] = (__bf16)a1.y; v[6] = (__bf16)a1.z; v[7] = (__bf16)a1.w;
  const int h = t >> 6, k8 = t & 63;
  *(bf16x8*)(Wbf + ((size_t)k8 * 512 + h) * 8) = v;  // scattered 16B: one-time
}

// ---------- K1: GEMM 64 rows x full 512 cols per block, atomic-free stats ----------
// 512 threads = 8 waves; wave w: col-tiles ct0=w*2..+2, row-tiles rt=0,1.
__global__ __launch_bounds__(512, 2) void gemm_k(const float* __restrict__ X,
                                                 const __bf16* __restrict__ Wbf,
                                                 unsigned short* __restrict__ Wxb,
                                                 float* __restrict__ partial) {
  __shared__ alignas(16) __bf16 As2[4][65][8];   // [kq][row(+pad)][k%8]
  __shared__ alignas(16) bf16x8 Bs2[2048];       // [kq][col][k%8] flat, linear-staged
  __shared__ float sred[2][kH];
  const int tid = threadIdx.x;
  const size_t row0 = (size_t)blockIdx.x * 64;
  const int w = tid >> 6, L = tid & 63;
  const int ct0 = w * 2;
  const int lhalf = L >> 5, l32 = L & 31;
  const int arow = tid >> 3, acol = (tid & 7) * 4;  // A staging: 1 float4/thread
  const int akq = acol >> 3, aoff = acol & 7;       // dest plane / half-chunk

  floatx16 acc[2][2] = {};
  const float* xbase = X + (row0 + arow) * kD + acol;
  float4 a_pre = *(const float4*)xbase;  // slab 0

#pragma unroll 1
  for (int s = 0; s < 16; ++s) {
    __syncthreads();  // prior MFMA ds_reads done before LDS overwrite
    bf16x4 av;
    av[0] = (__bf16)a_pre.x; av[1] = (__bf16)a_pre.y;
    av[2] = (__bf16)a_pre.z; av[3] = (__bf16)a_pre.w;
    *(bf16x4*)&As2[akq][arow][aoff] = av;
#pragma unroll
    for (int j = 0; j < 4; ++j) {
      const int ci = j * 512 + tid;  // slab-local 16B-chunk index (linear)
      gld_lds16(Wbf + ((size_t)s * 2048 + ci) * 8, (char*)&Bs2[0] + (size_t)ci * 16);
    }
    __syncthreads();  // vmcnt(0)+lgkmcnt(0): staging complete
    if (s < 15) a_pre = *(const float4*)(xbase + (s + 1) * 32);  // overlaps MFMA
#pragma unroll
    for (int kh = 0; kh < 2; ++kh) {
      const int kq = kh * 2 + lhalf;
      const bf16x8 af0 = *(const bf16x8*)&As2[kq][l32][0];
      const bf16x8 af1 = *(const bf16x8*)&As2[kq][32 + l32][0];
      const bf16x8 b0 = Bs2[kq * 512 + ct0 * 32 + l32];
      const bf16x8 b1 = Bs2[kq * 512 + (ct0 + 1) * 32 + l32];
      acc[0][0] = __builtin_amdgcn_mfma_f32_32x32x16_bf16(af0, b0, acc[0][0], 0, 0, 0);
      acc[0][1] = __builtin_amdgcn_mfma_f32_32x32x16_bf16(af0, b1, acc[0][1], 0, 0, 0);
      acc[1][0] = __builtin_amdgcn_mfma_f32_32x32x16_bf16(af1, b0, acc[1][0], 0, 0, 0);
      acc[1][1] = __builtin_amdgcn_mfma_f32_32x32x16_bf16(af1, b1, acc[1][1], 0, 0, 0);
    }
  }

  // ---- epilogue 1: column sums/sumsq -> LDS -> plain partial stores ----
  __syncthreads();
  sred[0][tid] = 0.f;
  sred[1][tid] = 0.f;
  __syncthreads();
#pragma unroll
  for (int c = 0; c < 2; ++c) {
    float s = 0.f, q = 0.f;
#pragma unroll
    for (int rt = 0; rt < 2; ++rt) {
#pragma unroll
      for (int r = 0; r < 16; ++r) {
        const float v = acc[rt][c][r];
        s += v;
        q += v * v;
      }
    }
    s += __shfl_xor(s, 32);
    q += __shfl_xor(q, 32);
    if (lhalf == 0) {
      atomicAdd(&sred[0][(ct0 + c) * 32 + l32], s);  // LDS atomics only
      atomicAdd(&sred[1][(ct0 + c) * 32 + l32], q);
    }
  }
  // ---- epilogue 2: store Wx bf16, packed dword pairs via shfl ----
  // C/D layout (32x32): col = lane&31, row = 4*(lane>>5) + (reg&3) + 8*(reg>>2)
#pragma unroll
  for (int rt = 0; rt < 2; ++rt) {
#pragma unroll
    for (int c = 0; c < 2; ++c) {
      const int col = (ct0 + c) * 32 + l32;
#pragma unroll
      for (int r = 0; r < 16; ++r) {
        const int row = rt * 32 + 4 * lhalf + (r & 3) + 8 * (r >> 2);
        const unsigned short u = __builtin_bit_cast(unsigned short, (__bf16)acc[rt][c][r]);
        const unsigned un = __shfl_down((unsigned)u, 1);
        if ((l32 & 1) == 0)
          *(unsigned*)(Wxb + (row0 + row) * (size_t)kH + col) = (unsigned)u | (un << 16);
      }
    }
  }
  __syncthreads();
  partial[(size_t)blockIdx.x * 1024 + tid] = sred[0][tid];
  partial[(size_t)blockIdx.x * 1024 + 512 + tid] = sred[1][tid];
}

// ---------- K2: reduce per-block partials (40 blocks x 25 rows) ----------
__global__ __launch_bounds__(512) void red1_k(const float* __restrict__ partial,
                                              float* __restrict__ sums) {
  const int tid = threadIdx.x;
  const int r0 = blockIdx.x * 25;
  float s0 = 0.f, s1 = 0.f;
#pragma unroll 5
  for (int r = 0; r < 25; ++r) {
    s0 += partial[(size_t)(r0 + r) * 1024 + tid];
    s1 += partial[(size_t)(r0 + r) * 1024 + 512 + tid];
  }
  atomicAdd(&sums[tid], s0);        // 40-deep contention: negligible
  atomicAdd(&sums[kH + tid], s1);
}

// ---------- K3: finalize BN scale/shift + alpha params ----------
// prm: [0]=scale [512]=shift [1024]=a [1536]=1-a [2048]=a^L
__global__ __launch_bounds__(512) void finalize_k(const float* __restrict__ sums,
                                                  const float* __restrict__ alpha,
                                                  const float* __restrict__ gamma,
                                                  const float* __restrict__ beta,
                                                  float* __restrict__ prm) {
  const int h = threadIdx.x;
  const float inv_n = 1.0f / (float)kM;
  const float mean = sums[h] * inv_n;
  const float var = sums[kH + h] * inv_n - mean * mean;
  const float sc = gamma[h] * rsqrtf(var + 1e-5f);
  const float sh = beta[h] - mean * sc;
  const float a = clipa(alpha[h]);
  prm[h] = sc;
  prm[kH + h] = sh;
  prm[2 * kH + h] = a;
  prm[3 * kH + h] = 1.0f - a;
  prm[4 * kH + h] = pow20(a);
}

// ---------- K4: per-chunk RAW EWMA (no BN dep -> runs right after gemm) ----------
__global__ __launch_bounds__(512) void agg_raw_k(const unsigned short* __restrict__ Wxb,
                                                 const float* __restrict__ alpha,
                                                 float* __restrict__ vbuf) {
  const int bc = blockIdx.x;
  const int b = bc / kC, c = bc % kC;
  const int h = threadIdx.x;
  const float a = clipa(alpha[h]);
  const float oma = 1.0f - a;
  const unsigned short* base = Wxb + ((size_t)b * kT + (size_t)c * kL) * kH + h;
  float v = 0.f;
#pragma unroll
  for (int i = 0; i < kL; ++i)
    v = a * v + oma * bf2f(base[(size_t)i * kH]);
  vbuf[(size_t)bc * kH + h] = v;
}

// ---------- K5: chunk-boundary scan, BN folded: u' = a^20 u + sc*v + sh*(1-a^20) ----------
__global__ __launch_bounds__(512) void scan_k(const float* __restrict__ ut0,
                                              const float* __restrict__ alpha,
                                              const float* __restrict__ prm,
                                              float* __restrict__ vbuf) {
  const int b = blockIdx.x;
  const int h = threadIdx.x;
  const float a20 = pow20(clipa(alpha[h]));
  const float sc = prm[h];
  const float shc = prm[kH + h] * (1.0f - a20);
  float u = ut0[(size_t)b * kH + h];
  float vc[10];
#pragma unroll 1
  for (int cb = 0; cb < kC; cb += 10) {
#pragma unroll
    for (int j = 0; j < 10; ++j)
      vc[j] = vbuf[((size_t)b * kC + cb + j) * kH + h];  // independent, pipelined
#pragma unroll
    for (int j = 0; j < 10; ++j) {
      vbuf[((size_t)b * kC + cb + j) * kH + h] = u;      // ustart for chunk
      u = a20 * u + sc * vc[j] + shc;
    }
  }
}

// ---------- K6: per-chunk softmax accumulation -> partial store ----------
__global__ __launch_bounds__(512) void soft_k(const unsigned short* __restrict__ Wxb,
                                              const float* __restrict__ prm,
                                              const float* __restrict__ ustart,
                                              float* __restrict__ accp) {
  __shared__ float part[kL][9];
  __shared__ float zinv[kL];
  const int bc = blockIdx.x;
  const int b = bc / kC, c = bc % kC;
  const int h = threadIdx.x;
  const int wv = h >> 6, lane = h & 63;
  const float sc = prm[h], sh = prm[kH + h];
  const float a = prm[2 * kH + h], oma = prm[3 * kH + h];
  float u = ustart[(size_t)bc * kH + h];
  const unsigned short* base = Wxb + ((size_t)b * kT + (size_t)c * kL) * kH + h;
  float e[kL];
#pragma unroll
  for (int i = 0; i < kL; ++i) {
    const float wvx = bf2f(base[(size_t)i * kH]) * sc + sh;
    u = a * u + oma * wvx;
    e[i] = __expf(u);  // |u| <~ 2 after BN+EWMA damping: no max-subtract needed
  }
#pragma unroll
  for (int i = 0; i < kL; ++i) {
    float s = e[i];
#pragma unroll
    for (int off = 32; off > 0; off >>= 1) s += __shfl_xor(s, off);
    if (lane == 0) part[i][wv] = s;
  }
  __syncthreads();
  if (h < kL) {
    float s = 0.f;
#pragma unroll
    for (int j = 0; j < 8; ++j) s += part[h][j];
    zinv[h] = 1.0f / s;
  }
  __syncthreads();
  float acc = 0.f;
#pragma unroll
  for (int i = 0; i < kL; ++i) acc += e[i] * zinv[i];
  accp[(size_t)bc * kH + h] = acc;
}

// ---------- K7: reduce chunk partials -> out ----------
__global__ __launch_bounds__(512) void out_red_k(const float* __restrict__ accp,
                                                 float* __restrict__ out) {
  const int b = blockIdx.x;
  const int h = threadIdx.x;
  float s = 0.f;
#pragma unroll 4
  for (int c = 0; c < kC; ++c) s += accp[((size_t)b * kC + c) * kH + h];
  out[(size_t)b * kH + h] = s;
}

}  // namespace

extern "C" void kernel_launch(void* const* d_in, const int* in_sizes, int n_in,
                              void* d_out, int out_size, void* d_ws, size_t ws_size,
                              hipStream_t stream) {
  const float* x = (const float*)d_in[0];      // [32,2000,512]
  const float* Wm = (const float*)d_in[1];     // [512,512]
  // d_in[2] = b: unused — BN mean subtraction cancels the bias exactly
  const float* alpha = (const float*)d_in[3];
  const float* gamma = (const float*)d_in[4];
  const float* beta = (const float*)d_in[5];
  const float* ut0 = (const float*)d_in[6];
  float* out = (float*)d_out;                  // [32,1,512]

  float* wsp = (float*)d_ws;
  float* vbuf = wsp;                                   // 3200*512 f
  float* accp = vbuf + (size_t)kB * kC * kH;           // 3200*512 f
  float* partial = accp + (size_t)kB * kC * kH;        // 1000*1024 f
  float* sums = partial + (size_t)1000 * 1024;         // 1024 f
  float* prm = sums + 2 * kH;                          // 2560 f
  __bf16* Wbf = (__bf16*)(prm + 5 * kH);               // 262144 bf16 (16B-aligned)
  unsigned short* Wxb = (unsigned short*)(Wbf + (size_t)kH * kD);  // 65.5 MB

  hipMemsetAsync(sums, 0, 2 * kH * sizeof(float), stream);
  wcvt_k<<<128, 256, 0, stream>>>(Wm, Wbf);
  gemm_k<<<kM / 64, 512, 0, stream>>>(x, Wbf, Wxb, partial);
  agg_raw_k<<<kB * kC, 512, 0, stream>>>(Wxb, alpha, vbuf);   // L3-hot Wxb
  red1_k<<<40, 512, 0, stream>>>(partial, sums);
  finalize_k<<<1, 512, 0, stream>>>(sums, alpha, gamma, beta, prm);
  scan_k<<<kB, 512, 0, stream>>>(ut0, alpha, prm, vbuf);
  soft_k<<<kB * kC, 512, 0, stream>>>(Wxb, prm, vbuf, accp);
  out_red_k<<<kB, 512, 0, stream>>>(accp, out);
}

// Round 2
// 301.079 us; speedup vs baseline: 1.0653x; 1.0260x over previous
//
#include <hip/hip_runtime.h>
#include <hip/hip_bf16.h>
#include <stdint.h>

// ReadoutLayer: Wx = x @ W^T (+b cancels under BN), BatchNorm(train) over B*T,
// then ut = a*ut + (1-a)*wxn per t with acc += softmax(ut, axis=H).
// R6: gemm_k latency-bound, not conflict-bound (R5 post-mortem: conflicts 30x down,
// MfmaUtil DOWN 13->11.7%, all pipes idle, ~5500 cy/slab vs ~700 cy of work).
// Restructure: BM=128 (2x arithmetic intensity, 500 blocks), double-buffered LDS,
// ONE raw s_barrier per slab with counted s_waitcnt vmcnt(2) (T3-minimum recipe):
// B gld_lds(s+1) + X prefetch(s+2) issued before MFMA(s); barrier drains only B.
// Fragment LDS layout identical to R5 (conflict-free, bit-identical math).

namespace {
constexpr int kB = 32;
constexpr int kT = 2000;
constexpr int kD = 512;
constexpr int kH = 512;
constexpr int kM = kB * kT;   // 64000 rows
constexpr int kBM = 128;      // rows per block
constexpr int kNB = kM / kBM; // 500 blocks
constexpr int kL = 20;        // chunk length
constexpr int kC = kT / kL;   // 100 chunks per batch
constexpr float kALo = 0.81873075307798182f;  // exp(-1/5)
constexpr float kAHi = 0.96078943915232320f;  // exp(-1/25)

typedef __bf16 bf16x4 __attribute__((ext_vector_type(4)));
typedef __bf16 bf16x8 __attribute__((ext_vector_type(8)));
typedef float floatx16 __attribute__((ext_vector_type(16)));

__device__ __forceinline__ float bf2f(unsigned short u) {
  return __builtin_bit_cast(float, (unsigned)u << 16);
}
__device__ __forceinline__ float clipa(float a) {
  return fminf(fmaxf(a, kALo), kAHi);
}
__device__ __forceinline__ float pow20(float a) {
  const float a2 = a * a, a4 = a2 * a2, a5 = a4 * a;
  const float a10 = a5 * a5;
  return a10 * a10;
}
// async global->LDS, 16B per lane; LDS dest = wave-uniform base + lane*16
__device__ __forceinline__ void gld_lds16(const void* g, void* l) {
  __builtin_amdgcn_global_load_lds(
      (const __attribute__((address_space(1))) uint32_t*)g,
      (__attribute__((address_space(3))) uint32_t*)(uintptr_t)l, 16, 0, 0);
}

// ---------- K0: W f32 -> bf16, permuted to Wbf2[k8][h][8] (k8 = k/8) ----------
// Slab-local 16B-chunk index kq*512+h is linear in global chunk k8*512+h, so
// gemm B-staging reads lane-consecutive 16B chunks -> linear LDS dest.
__global__ __launch_bounds__(256) void wcvt_k(const float* __restrict__ W,
                                              __bf16* __restrict__ Wbf) {
  const int t = blockIdx.x * 256 + threadIdx.x;  // t = h*64 + k8
  const float4 a0 = ((const float4*)W)[t * 2];
  const float4 a1 = ((const float4*)W)[t * 2 + 1];
  bf16x8 v;
  v[0] = (__bf16)a0.x; v[1] = (__bf16)a0.y; v[2] = (__bf16)a0.z; v[3] = (__bf16)a0.w;
  v[4] = (__bf16)a1.x; v[5] = (__bf16)a1.y; v[6] = (__bf16)a1.z; v[7] = (__bf16)a1.w;
  const int h = t >> 6, k8 = t & 63;
  *(bf16x8*)(Wbf + ((size_t)k8 * 512 + h) * 8) = v;  // scattered 16B: one-time
}

// ---------- K1: GEMM 128 rows x 512 cols per block, 2-phase pipelined ----------
// 512 threads = 8 waves; wave w: col-tiles ct0=w*2..+2, row-tiles rt=0..3.
// acc[4][2] = 128 VGPR; ~1 block/CU (intended: fat block, deep per-wave ILP).
__global__ __launch_bounds__(512, 2) void gemm_k(const float* __restrict__ X,
                                                 const __bf16* __restrict__ Wbf,
                                                 unsigned short* __restrict__ Wxb,
                                                 float* __restrict__ partial) {
  __shared__ alignas(16) __bf16 As2[2][4][128][8];  // [buf][kq][row][k%8], 2x8KB
  __shared__ alignas(16) bf16x8 Bs2[2][2048];       // [buf][kq*512+col], 2x32KB
  __shared__ float sred[2][kH];
  const int tid = threadIdx.x;
  const size_t row0 = (size_t)blockIdx.x * kBM;
  const int w = tid >> 6, L = tid & 63;
  const int ct0 = w * 2;
  const int lhalf = L >> 5, l32 = L & 31;
  const int arow = tid >> 2, akq = tid & 3;  // A staging: 8 f32 -> 1 bf16x8/thread

  floatx16 acc[4][2] = {};
  const float* xptr = X + (row0 + arow) * kD + akq * 8;

  // ---- prologue: stage slab 0 into buf 0, prefetch A regs for slab 1 ----
  float4 a0 = *(const float4*)xptr;
  float4 a1 = *(const float4*)(xptr + 4);
#pragma unroll
  for (int j = 0; j < 4; ++j) {
    const int ci = j * 512 + tid;
    gld_lds16(Wbf + (size_t)ci * 8, (char*)&Bs2[0][0] + (size_t)ci * 16);
  }
  {
    bf16x8 av;
    av[0] = (__bf16)a0.x; av[1] = (__bf16)a0.y; av[2] = (__bf16)a0.z; av[3] = (__bf16)a0.w;
    av[4] = (__bf16)a1.x; av[5] = (__bf16)a1.y; av[6] = (__bf16)a1.z; av[7] = (__bf16)a1.w;
    *(bf16x8*)&As2[0][akq][arow][0] = av;
  }
  a0 = *(const float4*)(xptr + 32);
  a1 = *(const float4*)(xptr + 36);
  asm volatile("s_waitcnt vmcnt(2) lgkmcnt(0)" ::: "memory");
  __builtin_amdgcn_s_barrier();

#pragma unroll 1
  for (int s = 0; s < 16; ++s) {
    const int buf = s & 1;
    if (s < 15) {
      // issue B(s+1) into buf^1 (stays in flight across MFMA phase)
#pragma unroll
      for (int j = 0; j < 4; ++j) {
        const int ci = j * 512 + tid;
        gld_lds16(Wbf + ((size_t)(s + 1) * 2048 + ci) * 8,
                  (char*)&Bs2[buf ^ 1][0] + (size_t)ci * 16);
      }
      // A(s+1) regs -> bf16 -> LDS (compiler waits the a0/a1 vmcnt precisely)
      bf16x8 av;
      av[0] = (__bf16)a0.x; av[1] = (__bf16)a0.y; av[2] = (__bf16)a0.z; av[3] = (__bf16)a0.w;
      av[4] = (__bf16)a1.x; av[5] = (__bf16)a1.y; av[6] = (__bf16)a1.z; av[7] = (__bf16)a1.w;
      *(bf16x8*)&As2[buf ^ 1][akq][arow][0] = av;
      if (s < 14) {  // X prefetch for slab s+2 rides through the barrier
        a0 = *(const float4*)(xptr + (s + 2) * 32);
        a1 = *(const float4*)(xptr + (s + 2) * 32 + 4);
      }
    }
    // ---- compute slab s from buf ----
#pragma unroll
    for (int kh = 0; kh < 2; ++kh) {
      const int kq = kh * 2 + lhalf;
      const bf16x8 af0 = *(const bf16x8*)&As2[buf][kq][l32][0];
      const bf16x8 af1 = *(const bf16x8*)&As2[buf][kq][32 + l32][0];
      const bf16x8 af2 = *(const bf16x8*)&As2[buf][kq][64 + l32][0];
      const bf16x8 af3 = *(const bf16x8*)&As2[buf][kq][96 + l32][0];
      const bf16x8 b0 = Bs2[buf][kq * 512 + ct0 * 32 + l32];
      const bf16x8 b1 = Bs2[buf][kq * 512 + (ct0 + 1) * 32 + l32];
      acc[0][0] = __builtin_amdgcn_mfma_f32_32x32x16_bf16(af0, b0, acc[0][0], 0, 0, 0);
      acc[0][1] = __builtin_amdgcn_mfma_f32_32x32x16_bf16(af0, b1, acc[0][1], 0, 0, 0);
      acc[1][0] = __builtin_amdgcn_mfma_f32_32x32x16_bf16(af1, b0, acc[1][0], 0, 0, 0);
      acc[1][1] = __builtin_amdgcn_mfma_f32_32x32x16_bf16(af1, b1, acc[1][1], 0, 0, 0);
      acc[2][0] = __builtin_amdgcn_mfma_f32_32x32x16_bf16(af2, b0, acc[2][0], 0, 0, 0);
      acc[2][1] = __builtin_amdgcn_mfma_f32_32x32x16_bf16(af2, b1, acc[2][1], 0, 0, 0);
      acc[3][0] = __builtin_amdgcn_mfma_f32_32x32x16_bf16(af3, b0, acc[3][0], 0, 0, 0);
      acc[3][1] = __builtin_amdgcn_mfma_f32_32x32x16_bf16(af3, b1, acc[3][1], 0, 0, 0);
    }
    if (s < 15) {
      // drain B(s+1) (+ ds ops); leave the 2 X-prefetch loads in flight
      if (s < 14)
        asm volatile("s_waitcnt vmcnt(2) lgkmcnt(0)" ::: "memory");
      else
        asm volatile("s_waitcnt vmcnt(0) lgkmcnt(0)" ::: "memory");
      __builtin_amdgcn_s_barrier();
    }
  }

  // ---- epilogue 1: column sums/sumsq -> LDS -> plain partial stores ----
  __syncthreads();
  sred[0][tid] = 0.f;
  sred[1][tid] = 0.f;
  __syncthreads();
#pragma unroll
  for (int c = 0; c < 2; ++c) {
    float s = 0.f, q = 0.f;
#pragma unroll
    for (int rt = 0; rt < 4; ++rt) {
#pragma unroll
      for (int r = 0; r < 16; ++r) {
        const float v = acc[rt][c][r];
        s += v;
        q += v * v;
      }
    }
    s += __shfl_xor(s, 32);
    q += __shfl_xor(q, 32);
    if (lhalf == 0) {
      atomicAdd(&sred[0][(ct0 + c) * 32 + l32], s);  // LDS atomics only
      atomicAdd(&sred[1][(ct0 + c) * 32 + l32], q);
    }
  }
  // ---- epilogue 2: store Wx bf16, packed dword pairs via shfl ----
  // C/D layout (32x32): col = lane&31, row = 4*(lane>>5) + (reg&3) + 8*(reg>>2)
#pragma unroll
  for (int rt = 0; rt < 4; ++rt) {
#pragma unroll
    for (int c = 0; c < 2; ++c) {
      const int col = (ct0 + c) * 32 + l32;
#pragma unroll
      for (int r = 0; r < 16; ++r) {
        const int row = rt * 32 + 4 * lhalf + (r & 3) + 8 * (r >> 2);
        const unsigned short u = __builtin_bit_cast(unsigned short, (__bf16)acc[rt][c][r]);
        const unsigned un = __shfl_down((unsigned)u, 1);
        if ((l32 & 1) == 0)
          *(unsigned*)(Wxb + (row0 + row) * (size_t)kH + col) = (unsigned)u | (un << 16);
      }
    }
  }
  __syncthreads();
  partial[(size_t)blockIdx.x * 1024 + tid] = sred[0][tid];
  partial[(size_t)blockIdx.x * 1024 + 512 + tid] = sred[1][tid];
}

// ---------- K2: reduce per-block partials (25 blocks x 20 rows = 500) ----------
__global__ __launch_bounds__(512) void red1_k(const float* __restrict__ partial,
                                              float* __restrict__ sums) {
  const int tid = threadIdx.x;
  const int r0 = blockIdx.x * 20;
  float s0 = 0.f, s1 = 0.f;
#pragma unroll 5
  for (int r = 0; r < 20; ++r) {
    s0 += partial[(size_t)(r0 + r) * 1024 + tid];
    s1 += partial[(size_t)(r0 + r) * 1024 + 512 + tid];
  }
  atomicAdd(&sums[tid], s0);        // 25-deep contention: negligible
  atomicAdd(&sums[kH + tid], s1);
}

// ---------- K3: finalize BN scale/shift + alpha params ----------
// prm: [0]=scale [512]=shift [1024]=a [1536]=1-a [2048]=a^L
__global__ __launch_bounds__(512) void finalize_k(const float* __restrict__ sums,
                                                  const float* __restrict__ alpha,
                                                  const float* __restrict__ gamma,
                                                  const float* __restrict__ beta,
                                                  float* __restrict__ prm) {
  const int h = threadIdx.x;
  const float inv_n = 1.0f / (float)kM;
  const float mean = sums[h] * inv_n;
  const float var = sums[kH + h] * inv_n - mean * mean;
  const float sc = gamma[h] * rsqrtf(var + 1e-5f);
  const float sh = beta[h] - mean * sc;
  const float a = clipa(alpha[h]);
  prm[h] = sc;
  prm[kH + h] = sh;
  prm[2 * kH + h] = a;
  prm[3 * kH + h] = 1.0f - a;
  prm[4 * kH + h] = pow20(a);
}

// ---------- K4: per-chunk RAW EWMA (no BN dep -> runs right after gemm) ----------
__global__ __launch_bounds__(512) void agg_raw_k(const unsigned short* __restrict__ Wxb,
                                                 const float* __restrict__ alpha,
                                                 float* __restrict__ vbuf) {
  const int bc = blockIdx.x;
  const int b = bc / kC, c = bc % kC;
  const int h = threadIdx.x;
  const float a = clipa(alpha[h]);
  const float oma = 1.0f - a;
  const unsigned short* base = Wxb + ((size_t)b * kT + (size_t)c * kL) * kH + h;
  float v = 0.f;
#pragma unroll
  for (int i = 0; i < kL; ++i)
    v = a * v + oma * bf2f(base[(size_t)i * kH]);
  vbuf[(size_t)bc * kH + h] = v;
}

// ---------- K5: chunk-boundary scan, BN folded: u' = a^20 u + sc*v + sh*(1-a^20) ----------
__global__ __launch_bounds__(512) void scan_k(const float* __restrict__ ut0,
                                              const float* __restrict__ alpha,
                                              const float* __restrict__ prm,
                                              float* __restrict__ vbuf) {
  const int b = blockIdx.x;
  const int h = threadIdx.x;
  const float a20 = pow20(clipa(alpha[h]));
  const float sc = prm[h];
  const float shc = prm[kH + h] * (1.0f - a20);
  float u = ut0[(size_t)b * kH + h];
  float vc[10];
#pragma unroll 1
  for (int cb = 0; cb < kC; cb += 10) {
#pragma unroll
    for (int j = 0; j < 10; ++j)
      vc[j] = vbuf[((size_t)b * kC + cb + j) * kH + h];  // independent, pipelined
#pragma unroll
    for (int j = 0; j < 10; ++j) {
      vbuf[((size_t)b * kC + cb + j) * kH + h] = u;      // ustart for chunk
      u = a20 * u + sc * vc[j] + shc;
    }
  }
}

// ---------- K6: per-chunk softmax accumulation -> partial store ----------
__global__ __launch_bounds__(512) void soft_k(const unsigned short* __restrict__ Wxb,
                                              const float* __restrict__ prm,
                                              const float* __restrict__ ustart,
                                              float* __restrict__ accp) {
  __shared__ float part[kL][9];
  __shared__ float zinv[kL];
  const int bc = blockIdx.x;
  const int b = bc / kC, c = bc % kC;
  const int h = threadIdx.x;
  const int wv = h >> 6, lane = h & 63;
  const float sc = prm[h], sh = prm[kH + h];
  const float a = prm[2 * kH + h], oma = prm[3 * kH + h];
  float u = ustart[(size_t)bc * kH + h];
  const unsigned short* base = Wxb + ((size_t)b * kT + (size_t)c * kL) * kH + h;
  float e[kL];
#pragma unroll
  for (int i = 0; i < kL; ++i) {
    const float wvx = bf2f(base[(size_t)i * kH]) * sc + sh;
    u = a * u + oma * wvx;
    e[i] = __expf(u);  // |u| <~ 2 after BN+EWMA damping: no max-subtract needed
  }
#pragma unroll
  for (int i = 0; i < kL; ++i) {
    float s = e[i];
#pragma unroll
    for (int off = 32; off > 0; off >>= 1) s += __shfl_xor(s, off);
    if (lane == 0) part[i][wv] = s;
  }
  __syncthreads();
  if (h < kL) {
    float s = 0.f;
#pragma unroll
    for (int j = 0; j < 8; ++j) s += part[h][j];
    zinv[h] = 1.0f / s;
  }
  __syncthreads();
  float acc = 0.f;
#pragma unroll
  for (int i = 0; i < kL; ++i) acc += e[i] * zinv[i];
  accp[(size_t)bc * kH + h] = acc;
}

// ---------- K7: reduce chunk partials -> out ----------
__global__ __launch_bounds__(512) void out_red_k(const float* __restrict__ accp,
                                                 float* __restrict__ out) {
  const int b = blockIdx.x;
  const int h = threadIdx.x;
  float s = 0.f;
#pragma unroll 4
  for (int c = 0; c < kC; ++c) s += accp[((size_t)b * kC + c) * kH + h];
  out[(size_t)b * kH + h] = s;
}

}  // namespace

extern "C" void kernel_launch(void* const* d_in, const int* in_sizes, int n_in,
                              void* d_out, int out_size, void* d_ws, size_t ws_size,
                              hipStream_t stream) {
  const float* x = (const float*)d_in[0];      // [32,2000,512]
  const float* Wm = (const float*)d_in[1];     // [512,512]
  // d_in[2] = b: unused — BN mean subtraction cancels the bias exactly
  const float* alpha = (const float*)d_in[3];
  const float* gamma = (const float*)d_in[4];
  const float* beta = (const float*)d_in[5];
  const float* ut0 = (const float*)d_in[6];
  float* out = (float*)d_out;                  // [32,1,512]

  float* wsp = (float*)d_ws;
  float* vbuf = wsp;                                   // 3200*512 f
  float* accp = vbuf + (size_t)kB * kC * kH;           // 3200*512 f
  float* partial = accp + (size_t)kB * kC * kH;        // 500*1024 f (alloc 1000)
  float* sums = partial + (size_t)1000 * 1024;         // 1024 f
  float* prm = sums + 2 * kH;                          // 2560 f
  __bf16* Wbf = (__bf16*)(prm + 5 * kH);               // 262144 bf16 (16B-aligned)
  unsigned short* Wxb = (unsigned short*)(Wbf + (size_t)kH * kD);  // 65.5 MB

  hipMemsetAsync(sums, 0, 2 * kH * sizeof(float), stream);
  wcvt_k<<<128, 256, 0, stream>>>(Wm, Wbf);
  gemm_k<<<kNB, 512, 0, stream>>>(x, Wbf, Wxb, partial);
  agg_raw_k<<<kB * kC, 512, 0, stream>>>(Wxb, alpha, vbuf);   // L3-hot Wxb
  red1_k<<<25, 512, 0, stream>>>(partial, sums);
  finalize_k<<<1, 512, 0, stream>>>(sums, alpha, gamma, beta, prm);
  scan_k<<<kB, 512, 0, stream>>>(ut0, alpha, prm, vbuf);
  soft_k<<<kB * kC, 512, 0, stream>>>(Wxb, prm, vbuf, accp);
  out_red_k<<<kB, 512, 0, stream>>>(accp, out);
}